// Round 11
// baseline (514.039 us; speedup 1.0000x reference)
//
#include <hip/hip_runtime.h>
#include <hip/hip_bf16.h>

#define H_ 128
#define W_ 128
#define HW_ 16384
#define B_ 16

using short8 = __attribute__((ext_vector_type(8))) short;
using f32x4  = __attribute__((ext_vector_type(4))) float;

__device__ __forceinline__ unsigned short f2b(float v) {
    __hip_bfloat16 h = __float2bfloat16(v);
    return *reinterpret_cast<unsigned short*>(&h);
}
__device__ __forceinline__ float b2f(unsigned short u) {
    __hip_bfloat16 h = *reinterpret_cast<__hip_bfloat16*>(&u);
    return __bfloat162float(h);
}

// ---------------------------------------------------------------------------
// x [B][32][H][W] f32  ->  xc [B][H][W][32] bf16
// ---------------------------------------------------------------------------
__global__ __launch_bounds__(256) void to_nhwc(
    const float* __restrict__ x, unsigned short* __restrict__ xc)
{
    int p = blockIdx.x * 256 + threadIdx.x;           // 0 .. B*HW-1
    int b = p >> 14, rem = p & 16383;
    const float* src = x + (size_t)b * 32 * HW_ + rem;
    unsigned short ob[32];
    #pragma unroll
    for (int c = 0; c < 32; ++c) ob[c] = f2b(src[(size_t)c * HW_]);
    unsigned short* dst = xc + (size_t)p * 32;
    #pragma unroll
    for (int k = 0; k < 4; ++k)
        *reinterpret_cast<short8*>(dst + k * 8) = *reinterpret_cast<short8*>(&ob[k * 8]);
}

// ---------------------------------------------------------------------------
// w [co<63][CIN][KS][KS] f32 -> wt [tap][cb][kb(4)][co(64)][j(8)] bf16
// ci = cb*32 + kb*8 + j ; tap = ky*KS + kx ; co=63 zero-padded.
// ---------------------------------------------------------------------------
__global__ __launch_bounds__(256) void prep_w(
    const float* __restrict__ w, unsigned short* __restrict__ wt, int CIN, int KS)
{
    int NCB = CIN >> 5;
    int total = KS * KS * NCB * 4 * 64 * 8;
    for (int i = blockIdx.x * 256 + threadIdx.x; i < total; i += gridDim.x * 256) {
        int j  = i & 7;
        int co = (i >> 3) & 63;
        int kb = (i >> 9) & 3;
        int cb = (i >> 11) % NCB;
        int tap = (i >> 11) / NCB;
        int ky = tap / KS, kx = tap % KS;
        int ci = cb * 32 + kb * 8 + j;
        float v = (co < 63) ? w[((co * CIN + ci) * KS + ky) * KS + kx] : 0.f;
        wt[i] = f2b(v);
    }
}

// ---------------------------------------------------------------------------
// Implicit-GEMM conv. One block = 2 output rows x 128 px x 64 co = 256px x 64co.
// 4 waves, each 64 px x 64 co (A-frag:MFMA reuse 1:4, B-frag:MFMA 1:4).
// BOTH operands staged in LDS (round-10 counters: compiler sinks register
// "preloads" of weights back into the K-loop -> latency-serialized at
// MfmaUtil 6%; LDS staging is not defeatable). K-loop is pure ds_read+MFMA:
// 8 ds_read_b128 (~96cyc) vs 16 MFMA (~78cyc) per iter per wave.
// Staging is issue-all-loads-then-write (T14): ~34 independent 16B global
// loads in flight per thread, then ds_writes.
// A-tile padded CPP=C8+1 -> all LDS access patterns uniform 8 lanes/16B-slot.
// MFMA mapping (m89/m91): A lane l -> row l&15, k-oct l>>4; B lane l ->
// col l&15, k-oct l>>4; D lane l -> col l&15, row 4*(l>>4)+reg.
// ---------------------------------------------------------------------------
template<int CIN, int KS, int PAD>
__global__ __launch_bounds__(256) void conv_mfma(
    const unsigned short* __restrict__ in,   // NHWC bf16 [B][H][W][CIN]
    const unsigned short* __restrict__ wt,   // packed weights
    unsigned short* __restrict__ outp,       // NHWC bf16 [B][H][W][64]
    float* __restrict__ sums)                // [0..63]=sum, [64..127]=sumsq
{
    constexpr int NCB   = CIN / 32;
    constexpr int XCOLS = W_ + 2 * PAD;
    constexpr int TAPS  = KS * KS;
    constexpr int NK    = TAPS * NCB;      // K-iterations; also W chunks/thread
    constexpr int C8    = CIN / 8;         // real 16B chunks per position
    constexpr int CPP   = C8 + 1;          // +1 pad chunk per position
    constexpr int IROWS = KS + 1;          // input rows staged (2 out rows)
    constexpr int ROWCH = W_ * C8;         // real chunks per input row
    constexpr int NA    = IROWS * ROWCH / 256;  // A chunks per thread

    __shared__ short8 xs[IROWS * XCOLS * CPP];
    __shared__ short8 wl[NK * 256];

    const int b  = blockIdx.x >> 6;
    const int y0 = (blockIdx.x & 63) * 2;
    const int t  = threadIdx.x;
    const int lane = t & 63;
    const int wv = t >> 6;
    const int r0 = wv >> 1;                 // output row within block (0/1)
    const int xbase = (wv & 1) * 64;        // x base of this wave
    const int l15 = lane & 15;
    const int q = lane >> 4;

    // ---- staging: issue ALL global loads first (depth), then LDS writes ----
    const short8* in8 = reinterpret_cast<const short8*>(in);
    const short8* wt8 = reinterpret_cast<const short8*>(wt);

    short8 rA[NA];
    #pragma unroll
    for (int i = 0; i < NA; ++i) {
        const int idx = i * 256 + t;
        const int rr = idx / ROWCH;
        const int k  = idx - rr * ROWCH;
        const int yy = y0 - PAD + rr;
        short8 v = {};
        if (yy >= 0 && yy < H_)
            v = in8[(size_t)(b * H_ + yy) * ROWCH + k];
        rA[i] = v;
    }
    short8 rW[NK];
    #pragma unroll
    for (int j = 0; j < NK; ++j)
        rW[j] = wt8[j * 256 + t];

    #pragma unroll
    for (int i = 0; i < NA; ++i) {
        const int idx = i * 256 + t;
        const int rr = idx / ROWCH;
        const int k  = idx - rr * ROWCH;
        const int pos = k / C8 + PAD;
        const int slot = k - (k / C8) * C8;
        xs[(rr * XCOLS + pos) * CPP + slot] = rA[i];
    }
    #pragma unroll
    for (int j = 0; j < NK; ++j)
        wl[j * 256 + t] = rW[j];

    if constexpr (PAD) {   // halo columns pos=0 and pos=XCOLS-1
        short8 z = {};
        for (int i = t; i < IROWS * 2 * C8; i += 256) {
            const int rr = i / (2 * C8);
            const int rest = i % (2 * C8);
            const int pos = (rest / C8) ? (XCOLS - 1) : 0;
            const int slot = rest % C8;
            xs[(rr * XCOLS + pos) * CPP + slot] = z;
        }
    }
    __syncthreads();

    f32x4 acc[4][4];                        // [f(16px)][cf(16co)]
    #pragma unroll
    for (int f = 0; f < 4; ++f)
        #pragma unroll
        for (int cf = 0; cf < 4; ++cf)
            #pragma unroll
            for (int r = 0; r < 4; ++r) acc[f][cf][r] = 0.f;

    #pragma unroll
    for (int tap = 0; tap < TAPS; ++tap) {
        const int ky = tap / KS, kx = tap % KS;
        #pragma unroll
        for (int cb = 0; cb < NCB; ++cb) {
            const int tc = tap * NCB + cb;
            short8 bf[4];
            #pragma unroll
            for (int cf = 0; cf < 4; ++cf)
                bf[cf] = wl[(tc * 4 + q) * 64 + cf * 16 + l15];
            short8 af[4];
            #pragma unroll
            for (int f = 0; f < 4; ++f) {
                const int pos = xbase + f * 16 + l15 + kx;
                af[f] = xs[((r0 + ky) * XCOLS + pos) * CPP + cb * 4 + q];
            }
            #pragma unroll
            for (int f = 0; f < 4; ++f)
                #pragma unroll
                for (int cf = 0; cf < 4; ++cf)
                    acc[f][cf] = __builtin_amdgcn_mfma_f32_16x16x32_bf16(
                        af[f], bf[cf], acc[f][cf], 0, 0, 0);
        }
    }

    // ---- store (bf16 NHWC) + BN partial stats ----
    float sacc[4] = {0.f, 0.f, 0.f, 0.f}, qacc[4] = {0.f, 0.f, 0.f, 0.f};
    const size_t obase = ((size_t)(b * H_ + y0 + r0) * W_) * 64;
    #pragma unroll
    for (int f = 0; f < 4; ++f)
        #pragma unroll
        for (int cf = 0; cf < 4; ++cf)
            #pragma unroll
            for (int r = 0; r < 4; ++r) {
                float v = acc[f][cf][r];
                int x = xbase + f * 16 + q * 4 + r;
                int co = cf * 16 + l15;
                outp[obase + (size_t)x * 64 + co] = f2b(v);
                sacc[cf] += v;
                qacc[cf] = fmaf(v, v, qacc[cf]);
            }
    #pragma unroll
    for (int cf = 0; cf < 4; ++cf) {
        float s = sacc[cf], qq = qacc[cf];
        s += __shfl_xor(s, 16); qq += __shfl_xor(qq, 16);
        s += __shfl_xor(s, 32); qq += __shfl_xor(qq, 32);
        if (q == 0) {
            int co = cf * 16 + l15;
            atomicAdd(&sums[co], s);
            atomicAdd(&sums[64 + co], qq);
        }
    }
}

// ---------------------------------------------------------------------------
__global__ void finalize_stats(const float* __restrict__ sums, float* __restrict__ murs)
{
    int set = blockIdx.x, c = threadIdx.x;
    const float invN = 1.f / (16.f * 16384.f);
    float s = sums[set * 128 + c];
    float qv = sums[set * 128 + 64 + c];
    float mu = s * invN;
    float var = qv * invN - mu * mu;
    murs[set * 128 + c] = mu;
    murs[set * 128 + 64 + c] = rsqrtf(fmaxf(var, 0.f) + 1e-5f);
}

// ---------------------------------------------------------------------------
// h = project(relu(BN(s1)))  NHWC bf16 (ch0 = time)
// ---------------------------------------------------------------------------
__global__ __launch_bounds__(256) void epi1(
    const unsigned short* __restrict__ s1, const float* __restrict__ murs,
    const float* __restrict__ g, const float* __restrict__ bt,
    unsigned short* __restrict__ h)
{
    int p = blockIdx.x * 256 + threadIdx.x;
    const unsigned short* sp = s1 + (size_t)p * 64;
    unsigned short ib[64], ob[64];
    #pragma unroll
    for (int k = 0; k < 8; ++k)
        *reinterpret_cast<short8*>(&ib[k * 8]) = *reinterpret_cast<const short8*>(sp + k * 8);
    float ssq = 0.f;
    #pragma unroll
    for (int c = 0; c < 63; ++c) {
        float v = b2f(ib[c]);
        v = g[c] * ((v - murs[c]) * murs[64 + c]) + bt[c];
        v = fmaxf(v, 0.f);
        ssq = fmaf(v, v, ssq);
        ob[c + 1] = f2b(v);
    }
    ob[0] = f2b(sqrtf(1.f + ssq));
    unsigned short* hp = h + (size_t)p * 64;
    #pragma unroll
    for (int k = 0; k < 8; ++k)
        *reinterpret_cast<short8*>(hp + k * 8) = *reinterpret_cast<short8*>(&ob[k * 8]);
}

// ---------------------------------------------------------------------------
// out = project(relu(BN(s2) + BN(sp)))  -> f32 NCHW (ch0 = time)
// ---------------------------------------------------------------------------
__global__ __launch_bounds__(256) void epi2(
    const unsigned short* __restrict__ s2, const unsigned short* __restrict__ spb,
    const float* __restrict__ murs2, const float* __restrict__ mursp,
    const float* __restrict__ g2, const float* __restrict__ bt2,
    const float* __restrict__ gp, const float* __restrict__ btp,
    float* __restrict__ out)
{
    int p = blockIdx.x * 256 + threadIdx.x;
    int b = p >> 14, rem = p & 16383;
    unsigned short i2[64], ip[64];
    #pragma unroll
    for (int k = 0; k < 8; ++k) {
        *reinterpret_cast<short8*>(&i2[k * 8]) =
            *reinterpret_cast<const short8*>(s2 + (size_t)p * 64 + k * 8);
        *reinterpret_cast<short8*>(&ip[k * 8]) =
            *reinterpret_cast<const short8*>(spb + (size_t)p * 64 + k * 8);
    }
    float* ob = out + (size_t)b * 64 * HW_ + rem;
    float ssq = 0.f;
    #pragma unroll
    for (int c = 0; c < 63; ++c) {
        float v2 = b2f(i2[c]);
        v2 = g2[c] * ((v2 - murs2[c]) * murs2[64 + c]) + bt2[c];
        float vp = b2f(ip[c]);
        vp = gp[c] * ((vp - mursp[c]) * mursp[64 + c]) + btp[c];
        float r = fmaxf(v2 + vp, 0.f);
        ssq = fmaf(r, r, ssq);
        ob[(size_t)(c + 1) * HW_] = r;
    }
    ob[0] = sqrtf(1.f + ssq);
}

// ---------------------------------------------------------------------------
extern "C" void kernel_launch(void* const* d_in, const int* in_sizes, int n_in,
                              void* d_out, int out_size, void* d_ws, size_t ws_size,
                              hipStream_t stream)
{
    (void)in_sizes; (void)n_in; (void)out_size; (void)ws_size;
    const float* x   = (const float*)d_in[0];
    const float* w1  = (const float*)d_in[1];
    const float* g1  = (const float*)d_in[3];
    const float* bt1 = (const float*)d_in[4];
    const float* w2  = (const float*)d_in[5];
    const float* g2  = (const float*)d_in[7];
    const float* bt2 = (const float*)d_in[8];
    const float* wp  = (const float*)d_in[9];
    const float* gp  = (const float*)d_in[11];
    const float* btp = (const float*)d_in[12];
    // biases b1/b2/bp are mathematically dead: BN immediately follows each conv.
    float* out = (float*)d_out;
    char* ws = (char*)d_ws;

    // ws layout (bytes)
    unsigned short* xc  = (unsigned short*)(ws);                 // 16,777,216 B
    unsigned short* s1  = (unsigned short*)(ws + 16777216);      // 33,554,432 B (reused as sp)
    unsigned short* h   = (unsigned short*)(ws + 50331648);      // 33,554,432 B
    unsigned short* s2  = (unsigned short*)(ws + 83886080);      // 33,554,432 B
    unsigned short* w1t = (unsigned short*)(ws + 117440512);     //     36,864 B
    unsigned short* w2t = (unsigned short*)(ws + 117477376);     //     73,728 B
    unsigned short* wpt = (unsigned short*)(ws + 117551104);     //      4,096 B
    float* sums = (float*)(ws + 117555200);                      //      1,536 B
    float* murs = (float*)(ws + 117556736);                      //      1,536 B

    hipMemsetAsync(sums, 0, 1536, stream);
    to_nhwc<<<1024, 256, 0, stream>>>(x, xc);
    prep_w<<<72, 256, 0, stream>>>(w1, w1t, 32, 3);
    prep_w<<<144, 256, 0, stream>>>(w2, w2t, 64, 3);
    prep_w<<<8, 256, 0, stream>>>(wp, wpt, 32, 1);

    conv_mfma<32, 3, 1><<<1024, 256, 0, stream>>>(xc, w1t, s1, sums);
    finalize_stats<<<1, 64, 0, stream>>>(sums, murs);
    epi1<<<1024, 256, 0, stream>>>(s1, murs, g1, bt1, h);
    conv_mfma<64, 3, 1><<<1024, 256, 0, stream>>>(h, w2t, s2, sums + 128);
    conv_mfma<32, 1, 0><<<1024, 256, 0, stream>>>(xc, wpt, s1, sums + 256);  // sp reuses s1
    finalize_stats<<<2, 64, 0, stream>>>(sums + 128, murs + 128);
    epi2<<<1024, 256, 0, stream>>>(s2, s1, murs + 128, murs + 256,
                                   g2, bt2, gp, btp, out);
}

// Round 12
// 302.041 us; speedup vs baseline: 1.7019x; 1.7019x over previous
//
#include <hip/hip_runtime.h>
#include <hip/hip_bf16.h>

#define H_ 128
#define W_ 128
#define HW_ 16384
#define B_ 16

using short8 = __attribute__((ext_vector_type(8))) short;
using f32x4  = __attribute__((ext_vector_type(4))) float;

__device__ __forceinline__ unsigned short f2b(float v) {
    __hip_bfloat16 h = __float2bfloat16(v);
    return *reinterpret_cast<unsigned short*>(&h);
}
__device__ __forceinline__ float b2f(unsigned short u) {
    __hip_bfloat16 h = *reinterpret_cast<__hip_bfloat16*>(&u);
    return __bfloat162float(h);
}

// ---------------------------------------------------------------------------
// x [B][32][H][W] f32  ->  xc [B][H][W][32] bf16
// ---------------------------------------------------------------------------
__global__ __launch_bounds__(256) void to_nhwc(
    const float* __restrict__ x, unsigned short* __restrict__ xc)
{
    int p = blockIdx.x * 256 + threadIdx.x;           // 0 .. B*HW-1
    int b = p >> 14, rem = p & 16383;
    const float* src = x + (size_t)b * 32 * HW_ + rem;
    unsigned short ob[32];
    #pragma unroll
    for (int c = 0; c < 32; ++c) ob[c] = f2b(src[(size_t)c * HW_]);
    unsigned short* dst = xc + (size_t)p * 32;
    #pragma unroll
    for (int k = 0; k < 4; ++k)
        *reinterpret_cast<short8*>(dst + k * 8) = *reinterpret_cast<short8*>(&ob[k * 8]);
}

// ---------------------------------------------------------------------------
// w [co<63][CIN][KS][KS] f32 -> wt [tap][cb][kb(4)][co(64)][j(8)] bf16
// ci = cb*32 + kb*8 + j ; tap = ky*KS + kx ; co=63 zero-padded.
// ---------------------------------------------------------------------------
__global__ __launch_bounds__(256) void prep_w(
    const float* __restrict__ w, unsigned short* __restrict__ wt, int CIN, int KS)
{
    int NCB = CIN >> 5;
    int total = KS * KS * NCB * 4 * 64 * 8;
    for (int i = blockIdx.x * 256 + threadIdx.x; i < total; i += gridDim.x * 256) {
        int j  = i & 7;
        int co = (i >> 3) & 63;
        int kb = (i >> 9) & 3;
        int cb = (i >> 11) % NCB;
        int tap = (i >> 11) / NCB;
        int ky = tap / KS, kx = tap % KS;
        int ci = cb * 32 + kb * 8 + j;
        float v = (co < 63) ? w[((co * CIN + ci) * KS + ky) * KS + kx] : 0.f;
        wt[i] = f2b(v);
    }
}

// ---------------------------------------------------------------------------
// Implicit-GEMM conv. One block = 128 px x 64 co x 8 OUTPUT ROWS (sequential).
// Grid = B*H/8 = 256 blocks (1/CU). Round-11 post-mortem: per-block restaging
// at 1 wave/SIMD was latency-serialized (VGPR=132 proves the 34-deep load
// burst was compiler-sunk). Here: W staged ONCE per block; A kept in a 4-row
// LDS ring; per output row only ONE input row (NRC chunks/thread) is
// prefetched -- issued BEFORE the row's compute, ds-written AFTER (T14), one
// barrier per row. 4 waves, each 32px x 64co: per K-iter 6 ds_read_b128 +
// 8 MFMA, zero global ops.
// All LDS patterns uniform 8 lanes/16B-slot (CPP=C8+1 padding; audited).
// MFMA mapping (m89/m91): A lane l -> row l&15, k-oct l>>4; B lane l ->
// col l&15, k-oct l>>4; D lane l -> col l&15, row 4*(l>>4)+reg.
// ---------------------------------------------------------------------------
template<int CIN, int KS, int PAD>
__global__ __launch_bounds__(256) void conv_mfma(
    const unsigned short* __restrict__ in,   // NHWC bf16 [B][H][W][CIN]
    const unsigned short* __restrict__ wt,   // packed weights
    unsigned short* __restrict__ outp,       // NHWC bf16 [B][H][W][64]
    float* __restrict__ sums)                // [0..63]=sum, [64..127]=sumsq
{
    constexpr int NCB   = CIN / 32;
    constexpr int XCOLS = W_ + 2 * PAD;
    constexpr int TAPS  = KS * KS;
    constexpr int NK    = TAPS * NCB;       // K-iterations; W chunks/thread
    constexpr int C8    = CIN / 8;          // real 16B chunks per position
    constexpr int CPP   = C8 + 1;           // +1 pad chunk per position
    constexpr int ROWCH = W_ * C8;          // chunks per input row
    constexpr int NRC   = ROWCH / 256;      // row chunks per thread
    constexpr int NPRO  = 2 + PAD;          // prologue rows (covers y0 & y0+1)

    __shared__ short8 xs[4 * XCOLS * CPP];  // 4-row ring
    __shared__ short8 wl[NK * 256];

    const int bid = blockIdx.x;
    const int b  = bid >> 4;
    const int y0 = (bid & 15) * 8;
    const int t  = threadIdx.x;
    const int lane = t & 63;
    const int wv = t >> 6;
    const int xbase = wv * 32;
    const int l15 = lane & 15;
    const int q = lane >> 4;

    const short8* in8 = reinterpret_cast<const short8*>(in);
    const short8* wt8 = reinterpret_cast<const short8*>(wt);

    // ---- prologue: weights + first NPRO input rows, batched issue ----
    short8 rW[NK];
    #pragma unroll
    for (int j = 0; j < NK; ++j) rW[j] = wt8[j * 256 + t];
    short8 rP[NPRO][NRC];
    #pragma unroll
    for (int rr = 0; rr < NPRO; ++rr) {
        const int yy = y0 - PAD + rr;
        #pragma unroll
        for (int i = 0; i < NRC; ++i) {
            short8 v = {};
            if (yy >= 0 && yy < H_) v = in8[(size_t)(b * H_ + yy) * ROWCH + i * 256 + t];
            rP[rr][i] = v;
        }
    }
    #pragma unroll
    for (int j = 0; j < NK; ++j) wl[j * 256 + t] = rW[j];
    #pragma unroll
    for (int rr = 0; rr < NPRO; ++rr) {
        const int s = ((y0 - PAD + rr) + 4) & 3;
        #pragma unroll
        for (int i = 0; i < NRC; ++i) {
            const int k = i * 256 + t;
            xs[(s * XCOLS + k / C8 + PAD) * CPP + k % C8] = rP[rr][i];
        }
    }
    if constexpr (PAD) {   // halo columns (all 4 ring slots, written once)
        short8 z = {};
        for (int i = t; i < 4 * 2 * C8; i += 256) {
            const int s = i / (2 * C8), rest = i % (2 * C8);
            const int pos = (rest / C8) ? (XCOLS - 1) : 0;
            xs[(s * XCOLS + pos) * CPP + rest % C8] = z;
        }
    }
    __syncthreads();

    float sacc[4] = {0.f, 0.f, 0.f, 0.f}, qacc[4] = {0.f, 0.f, 0.f, 0.f};

    for (int y = y0; y < y0 + 8; ++y) {
        // -- issue prefetch of input row y+2 (consumed after compute) --
        short8 rA[NRC];
        const int yp = y + 2;
        #pragma unroll
        for (int i = 0; i < NRC; ++i) {
            short8 v = {};
            if (yp < H_) v = in8[(size_t)(b * H_ + yp) * ROWCH + i * 256 + t];
            rA[i] = v;
        }

        // -- compute output row y from ring --
        f32x4 acc[2][4];
        #pragma unroll
        for (int f = 0; f < 2; ++f)
            #pragma unroll
            for (int cf = 0; cf < 4; ++cf)
                #pragma unroll
                for (int r = 0; r < 4; ++r) acc[f][cf][r] = 0.f;

        #pragma unroll
        for (int tap = 0; tap < TAPS; ++tap) {
            const int ky = tap / KS, kx = tap % KS;
            const int sb = (((y + ky - PAD) + 4) & 3) * XCOLS;
            #pragma unroll
            for (int cb = 0; cb < NCB; ++cb) {
                const int tc = tap * NCB + cb;
                short8 bf[4];
                #pragma unroll
                for (int cf = 0; cf < 4; ++cf)
                    bf[cf] = wl[(tc * 4 + q) * 64 + cf * 16 + l15];
                short8 af[2];
                #pragma unroll
                for (int f = 0; f < 2; ++f) {
                    const int pos = xbase + f * 16 + l15 + kx;
                    af[f] = xs[(sb + pos) * CPP + cb * 4 + q];
                }
                #pragma unroll
                for (int f = 0; f < 2; ++f)
                    #pragma unroll
                    for (int cf = 0; cf < 4; ++cf)
                        acc[f][cf] = __builtin_amdgcn_mfma_f32_16x16x32_bf16(
                            af[f], bf[cf], acc[f][cf], 0, 0, 0);
            }
        }

        // -- store row + accumulate stats --
        const size_t obase = ((size_t)(b * H_ + y) * W_) * 64;
        #pragma unroll
        for (int f = 0; f < 2; ++f)
            #pragma unroll
            for (int cf = 0; cf < 4; ++cf)
                #pragma unroll
                for (int r = 0; r < 4; ++r) {
                    float v = acc[f][cf][r];
                    int x = xbase + f * 16 + q * 4 + r;
                    int co = cf * 16 + l15;
                    outp[obase + (size_t)x * 64 + co] = f2b(v);
                    sacc[cf] += v;
                    qacc[cf] = fmaf(v, v, qacc[cf]);
                }

        // -- ds-write prefetched row into ring slot (y+2)&3 (not read this row) --
        {
            const int s = (y + 2) & 3;
            #pragma unroll
            for (int i = 0; i < NRC; ++i) {
                const int k = i * 256 + t;
                xs[(s * XCOLS + k / C8 + PAD) * CPP + k % C8] = rA[i];
            }
        }
        __syncthreads();
    }

    #pragma unroll
    for (int cf = 0; cf < 4; ++cf) {
        float s = sacc[cf], qq = qacc[cf];
        s += __shfl_xor(s, 16); qq += __shfl_xor(qq, 16);
        s += __shfl_xor(s, 32); qq += __shfl_xor(qq, 32);
        if (q == 0) {
            int co = cf * 16 + l15;
            atomicAdd(&sums[co], s);
            atomicAdd(&sums[64 + co], qq);
        }
    }
}

// ---------------------------------------------------------------------------
__global__ void finalize_stats(const float* __restrict__ sums, float* __restrict__ murs)
{
    int set = blockIdx.x, c = threadIdx.x;
    const float invN = 1.f / (16.f * 16384.f);
    float s = sums[set * 128 + c];
    float qv = sums[set * 128 + 64 + c];
    float mu = s * invN;
    float var = qv * invN - mu * mu;
    murs[set * 128 + c] = mu;
    murs[set * 128 + 64 + c] = rsqrtf(fmaxf(var, 0.f) + 1e-5f);
}

// ---------------------------------------------------------------------------
// h = project(relu(BN(s1)))  NHWC bf16 (ch0 = time)
// ---------------------------------------------------------------------------
__global__ __launch_bounds__(256) void epi1(
    const unsigned short* __restrict__ s1, const float* __restrict__ murs,
    const float* __restrict__ g, const float* __restrict__ bt,
    unsigned short* __restrict__ h)
{
    int p = blockIdx.x * 256 + threadIdx.x;
    const unsigned short* sp = s1 + (size_t)p * 64;
    unsigned short ib[64], ob[64];
    #pragma unroll
    for (int k = 0; k < 8; ++k)
        *reinterpret_cast<short8*>(&ib[k * 8]) = *reinterpret_cast<const short8*>(sp + k * 8);
    float ssq = 0.f;
    #pragma unroll
    for (int c = 0; c < 63; ++c) {
        float v = b2f(ib[c]);
        v = g[c] * ((v - murs[c]) * murs[64 + c]) + bt[c];
        v = fmaxf(v, 0.f);
        ssq = fmaf(v, v, ssq);
        ob[c + 1] = f2b(v);
    }
    ob[0] = f2b(sqrtf(1.f + ssq));
    unsigned short* hp = h + (size_t)p * 64;
    #pragma unroll
    for (int k = 0; k < 8; ++k)
        *reinterpret_cast<short8*>(hp + k * 8) = *reinterpret_cast<short8*>(&ob[k * 8]);
}

// ---------------------------------------------------------------------------
// out = project(relu(BN(s2) + BN(sp)))  -> f32 NCHW (ch0 = time)
// ---------------------------------------------------------------------------
__global__ __launch_bounds__(256) void epi2(
    const unsigned short* __restrict__ s2, const unsigned short* __restrict__ spb,
    const float* __restrict__ murs2, const float* __restrict__ mursp,
    const float* __restrict__ g2, const float* __restrict__ bt2,
    const float* __restrict__ gp, const float* __restrict__ btp,
    float* __restrict__ out)
{
    int p = blockIdx.x * 256 + threadIdx.x;
    int b = p >> 14, rem = p & 16383;
    unsigned short i2[64], ip[64];
    #pragma unroll
    for (int k = 0; k < 8; ++k) {
        *reinterpret_cast<short8*>(&i2[k * 8]) =
            *reinterpret_cast<const short8*>(s2 + (size_t)p * 64 + k * 8);
        *reinterpret_cast<short8*>(&ip[k * 8]) =
            *reinterpret_cast<const short8*>(spb + (size_t)p * 64 + k * 8);
    }
    float* ob = out + (size_t)b * 64 * HW_ + rem;
    float ssq = 0.f;
    #pragma unroll
    for (int c = 0; c < 63; ++c) {
        float v2 = b2f(i2[c]);
        v2 = g2[c] * ((v2 - murs2[c]) * murs2[64 + c]) + bt2[c];
        float vp = b2f(ip[c]);
        vp = gp[c] * ((vp - mursp[c]) * mursp[64 + c]) + btp[c];
        float r = fmaxf(v2 + vp, 0.f);
        ssq = fmaf(r, r, ssq);
        ob[(size_t)(c + 1) * HW_] = r;
    }
    ob[0] = sqrtf(1.f + ssq);
}

// ---------------------------------------------------------------------------
extern "C" void kernel_launch(void* const* d_in, const int* in_sizes, int n_in,
                              void* d_out, int out_size, void* d_ws, size_t ws_size,
                              hipStream_t stream)
{
    (void)in_sizes; (void)n_in; (void)out_size; (void)ws_size;
    const float* x   = (const float*)d_in[0];
    const float* w1  = (const float*)d_in[1];
    const float* g1  = (const float*)d_in[3];
    const float* bt1 = (const float*)d_in[4];
    const float* w2  = (const float*)d_in[5];
    const float* g2  = (const float*)d_in[7];
    const float* bt2 = (const float*)d_in[8];
    const float* wp  = (const float*)d_in[9];
    const float* gp  = (const float*)d_in[11];
    const float* btp = (const float*)d_in[12];
    // biases b1/b2/bp are mathematically dead: BN immediately follows each conv.
    float* out = (float*)d_out;
    char* ws = (char*)d_ws;

    // ws layout (bytes)
    unsigned short* xc  = (unsigned short*)(ws);                 // 16,777,216 B
    unsigned short* s1  = (unsigned short*)(ws + 16777216);      // 33,554,432 B (reused as sp)
    unsigned short* h   = (unsigned short*)(ws + 50331648);      // 33,554,432 B
    unsigned short* s2  = (unsigned short*)(ws + 83886080);      // 33,554,432 B
    unsigned short* w1t = (unsigned short*)(ws + 117440512);     //     36,864 B
    unsigned short* w2t = (unsigned short*)(ws + 117477376);     //     73,728 B
    unsigned short* wpt = (unsigned short*)(ws + 117551104);     //      4,096 B
    float* sums = (float*)(ws + 117555200);                      //      1,536 B
    float* murs = (float*)(ws + 117556736);                      //      1,536 B

    hipMemsetAsync(sums, 0, 1536, stream);
    to_nhwc<<<1024, 256, 0, stream>>>(x, xc);
    prep_w<<<72, 256, 0, stream>>>(w1, w1t, 32, 3);
    prep_w<<<144, 256, 0, stream>>>(w2, w2t, 64, 3);
    prep_w<<<8, 256, 0, stream>>>(wp, wpt, 32, 1);

    conv_mfma<32, 3, 1><<<256, 256, 0, stream>>>(xc, w1t, s1, sums);
    finalize_stats<<<1, 64, 0, stream>>>(sums, murs);
    epi1<<<1024, 256, 0, stream>>>(s1, murs, g1, bt1, h);
    conv_mfma<64, 3, 1><<<256, 256, 0, stream>>>(h, w2t, s2, sums + 128);
    conv_mfma<32, 1, 0><<<256, 256, 0, stream>>>(xc, wpt, s1, sums + 256);  // sp reuses s1
    finalize_stats<<<2, 64, 0, stream>>>(sums + 128, murs + 128);
    epi2<<<1024, 256, 0, stream>>>(s2, s1, murs + 128, murs + 256,
                                   g2, bt2, gp, btp, out);
}

// Round 13
// 296.922 us; speedup vs baseline: 1.7312x; 1.0172x over previous
//
#include <hip/hip_runtime.h>
#include <hip/hip_bf16.h>

#define H_ 128
#define W_ 128
#define HW_ 16384
#define B_ 16

using short8 = __attribute__((ext_vector_type(8))) short;
using f32x4  = __attribute__((ext_vector_type(4))) float;

__device__ __forceinline__ unsigned short f2b(float v) {
    __hip_bfloat16 h = __float2bfloat16(v);
    return *reinterpret_cast<unsigned short*>(&h);
}
__device__ __forceinline__ float b2f(unsigned short u) {
    __hip_bfloat16 h = *reinterpret_cast<__hip_bfloat16*>(&u);
    return __bfloat162float(h);
}

// ---------------------------------------------------------------------------
// x [B][32][H][W] f32  ->  xc [B][H][W][32] bf16
// ---------------------------------------------------------------------------
__global__ __launch_bounds__(256) void to_nhwc(
    const float* __restrict__ x, unsigned short* __restrict__ xc)
{
    int p = blockIdx.x * 256 + threadIdx.x;           // 0 .. B*HW-1
    int b = p >> 14, rem = p & 16383;
    const float* src = x + (size_t)b * 32 * HW_ + rem;
    unsigned short ob[32];
    #pragma unroll
    for (int c = 0; c < 32; ++c) ob[c] = f2b(src[(size_t)c * HW_]);
    unsigned short* dst = xc + (size_t)p * 32;
    #pragma unroll
    for (int k = 0; k < 4; ++k)
        *reinterpret_cast<short8*>(dst + k * 8) = *reinterpret_cast<short8*>(&ob[k * 8]);
}

// ---------------------------------------------------------------------------
// w [co<63][CIN][KS][KS] f32 -> wt [tap][cb][kb(4)][co(64)][j(8)] bf16
// ci = cb*32 + kb*8 + j ; tap = ky*KS + kx ; co=63 zero-padded.
// ---------------------------------------------------------------------------
__global__ __launch_bounds__(256) void prep_w(
    const float* __restrict__ w, unsigned short* __restrict__ wt, int CIN, int KS)
{
    int NCB = CIN >> 5;
    int total = KS * KS * NCB * 4 * 64 * 8;
    for (int i = blockIdx.x * 256 + threadIdx.x; i < total; i += gridDim.x * 256) {
        int j  = i & 7;
        int co = (i >> 3) & 63;
        int kb = (i >> 9) & 3;
        int cb = (i >> 11) % NCB;
        int tap = (i >> 11) / NCB;
        int ky = tap / KS, kx = tap % KS;
        int ci = cb * 32 + kb * 8 + j;
        float v = (co < 63) ? w[((co * CIN + ci) * KS + ky) * KS + kx] : 0.f;
        wt[i] = f2b(v);
    }
}

// ---------------------------------------------------------------------------
// Implicit-GEMM conv. Block = 512 threads (8 waves = 2 waves/SIMD), covering
// 128 px x 64 co x 8 output rows, processed 2 rows per step.
// Round-12 post-mortem: 1 wave/SIMD left the kernel 4.5x above its
// LDS-throughput floor (MfmaUtil 13%, Occ 7.8%) -- latency exposure, not
// bandwidth. Here: same LDS footprint & traffic, but 2 waves/SIMD and a
// wider per-wave tile (64px x 32co: 6 independent ds_read_b128 + 8
// independent MFMAs per K-iter).
// Weights staged in LDS once per block; A in a 4-row ring; per step, the 2
// next input rows are global-loaded BEFORE compute and ds-written AFTER
// (T14), with compute -> barrier -> write -> barrier (replaced slots are
// read this step).
// All LDS patterns uniform 8 lanes/16B-slot (CPP=C8+1 padding; audited).
// MFMA mapping (m89/m91): A lane l -> row l&15, k-oct l>>4; B lane l ->
// col l&15, k-oct l>>4; D lane l -> col l&15, row 4*(l>>4)+reg.
// ---------------------------------------------------------------------------
template<int CIN, int KS, int PAD>
__global__ __launch_bounds__(512) void conv_mfma(
    const unsigned short* __restrict__ in,   // NHWC bf16 [B][H][W][CIN]
    const unsigned short* __restrict__ wt,   // packed weights
    unsigned short* __restrict__ outp,       // NHWC bf16 [B][H][W][64]
    float* __restrict__ sums)                // [0..63]=sum, [64..127]=sumsq
{
    constexpr int NCB   = CIN / 32;
    constexpr int XCOLS = W_ + 2 * PAD;
    constexpr int TAPS  = KS * KS;
    constexpr int NK    = TAPS * NCB;       // K-iterations
    constexpr int C8    = CIN / 8;          // real 16B chunks per position
    constexpr int CPP   = C8 + 1;           // +1 pad chunk per position
    constexpr int ROWCH = W_ * C8;          // chunks per input row
    constexpr int NRC   = ROWCH / 512;      // row chunks per thread
    constexpr int NPRO  = 2 + 2 * PAD;      // prologue rows
    constexpr int WCH   = NK * 256;         // weight chunks

    __shared__ short8 xs[4 * XCOLS * CPP];  // 4-row ring
    __shared__ short8 wl[WCH];

    const int bid = blockIdx.x;
    const int b  = bid >> 4;
    const int y0 = (bid & 15) * 8;
    const int t  = threadIdx.x;
    const int lane = t & 63;
    const int wv = t >> 6;                  // 0..7
    const int rsub = wv >> 2;               // row within step (0/1)
    const int xbase = ((wv >> 1) & 1) * 64; // px half
    const int cobase = (wv & 1) * 32;       // co half
    const int l15 = lane & 15;
    const int q = lane >> 4;

    const short8* in8 = reinterpret_cast<const short8*>(in);
    const short8* wt8 = reinterpret_cast<const short8*>(wt);

    // ---- prologue: weights + first NPRO input rows, batched issue ----
    constexpr int NW = (WCH + 511) / 512;
    short8 rW[NW];
    #pragma unroll
    for (int j0 = 0; j0 < WCH; j0 += 512) {
        short8 v = {};
        if (j0 + t < WCH) v = wt8[j0 + t];
        rW[j0 / 512] = v;
    }
    short8 rP[NPRO][NRC];
    #pragma unroll
    for (int rr = 0; rr < NPRO; ++rr) {
        const int yy = y0 - PAD + rr;
        #pragma unroll
        for (int i = 0; i < NRC; ++i) {
            short8 v = {};
            if (yy >= 0 && yy < H_) v = in8[(size_t)(b * H_ + yy) * ROWCH + i * 512 + t];
            rP[rr][i] = v;
        }
    }
    #pragma unroll
    for (int j0 = 0; j0 < WCH; j0 += 512)
        if (j0 + t < WCH) wl[j0 + t] = rW[j0 / 512];
    #pragma unroll
    for (int rr = 0; rr < NPRO; ++rr) {
        const int s = ((y0 - PAD + rr) + 4) & 3;
        #pragma unroll
        for (int i = 0; i < NRC; ++i) {
            const int k = i * 512 + t;
            xs[(s * XCOLS + k / C8 + PAD) * CPP + k % C8] = rP[rr][i];
        }
    }
    if constexpr (PAD) {   // halo columns (all 4 ring slots, written once)
        short8 z = {};
        for (int i = t; i < 4 * 2 * C8; i += 512) {
            const int s = i / (2 * C8), rest = i % (2 * C8);
            const int pos = (rest / C8) ? (XCOLS - 1) : 0;
            xs[(s * XCOLS + pos) * CPP + rest % C8] = z;
        }
    }
    __syncthreads();

    float sacc[2] = {0.f, 0.f}, qacc[2] = {0.f, 0.f};

    for (int y = y0; y < y0 + 8; y += 2) {
        // -- issue prefetch of the next 2 input rows (consumed after compute) --
        short8 rA[2][NRC];
        #pragma unroll
        for (int rr = 0; rr < 2; ++rr) {
            const int yp = y + 2 + PAD + rr;
            #pragma unroll
            for (int i = 0; i < NRC; ++i) {
                short8 v = {};
                if (yp < H_) v = in8[(size_t)(b * H_ + yp) * ROWCH + i * 512 + t];
                rA[rr][i] = v;
            }
        }

        // -- compute output row yr from ring --
        const int yr = y + rsub;
        f32x4 acc[4][2];
        #pragma unroll
        for (int f = 0; f < 4; ++f)
            #pragma unroll
            for (int cf = 0; cf < 2; ++cf)
                #pragma unroll
                for (int r = 0; r < 4; ++r) acc[f][cf][r] = 0.f;

        #pragma unroll
        for (int tap = 0; tap < TAPS; ++tap) {
            const int ky = tap / KS, kx = tap % KS;
            const int sb = (((yr + ky - PAD) + 4) & 3) * XCOLS;
            #pragma unroll
            for (int cb = 0; cb < NCB; ++cb) {
                const int tc = tap * NCB + cb;
                short8 bf[2];
                #pragma unroll
                for (int cf = 0; cf < 2; ++cf)
                    bf[cf] = wl[(tc * 4 + q) * 64 + cobase + cf * 16 + l15];
                short8 af[4];
                #pragma unroll
                for (int f = 0; f < 4; ++f) {
                    const int pos = xbase + f * 16 + l15 + kx;
                    af[f] = xs[(sb + pos) * CPP + cb * 4 + q];
                }
                #pragma unroll
                for (int f = 0; f < 4; ++f)
                    #pragma unroll
                    for (int cf = 0; cf < 2; ++cf)
                        acc[f][cf] = __builtin_amdgcn_mfma_f32_16x16x32_bf16(
                            af[f], bf[cf], acc[f][cf], 0, 0, 0);
            }
        }

        // -- store row + accumulate stats --
        const size_t obase = ((size_t)(b * H_ + yr) * W_) * 64;
        #pragma unroll
        for (int f = 0; f < 4; ++f)
            #pragma unroll
            for (int cf = 0; cf < 2; ++cf)
                #pragma unroll
                for (int r = 0; r < 4; ++r) {
                    float v = acc[f][cf][r];
                    int x = xbase + f * 16 + q * 4 + r;
                    int co = cobase + cf * 16 + l15;
                    outp[obase + (size_t)x * 64 + co] = f2b(v);
                    sacc[cf] += v;
                    qacc[cf] = fmaf(v, v, qacc[cf]);
                }

        __syncthreads();   // all ring reads done before overwriting slots

        #pragma unroll
        for (int rr = 0; rr < 2; ++rr) {
            const int s = (y + 2 + PAD + rr) & 3;
            #pragma unroll
            for (int i = 0; i < NRC; ++i) {
                const int k = i * 512 + t;
                xs[(s * XCOLS + k / C8 + PAD) * CPP + k % C8] = rA[rr][i];
            }
        }
        __syncthreads();   // writes visible for next step
    }

    #pragma unroll
    for (int cf = 0; cf < 2; ++cf) {
        float s = sacc[cf], qq = qacc[cf];
        s += __shfl_xor(s, 16); qq += __shfl_xor(qq, 16);
        s += __shfl_xor(s, 32); qq += __shfl_xor(qq, 32);
        if (q == 0) {
            int co = cobase + cf * 16 + l15;
            atomicAdd(&sums[co], s);
            atomicAdd(&sums[64 + co], qq);
        }
    }
}

// ---------------------------------------------------------------------------
__global__ void finalize_stats(const float* __restrict__ sums, float* __restrict__ murs)
{
    int set = blockIdx.x, c = threadIdx.x;
    const float invN = 1.f / (16.f * 16384.f);
    float s = sums[set * 128 + c];
    float qv = sums[set * 128 + 64 + c];
    float mu = s * invN;
    float var = qv * invN - mu * mu;
    murs[set * 128 + c] = mu;
    murs[set * 128 + 64 + c] = rsqrtf(fmaxf(var, 0.f) + 1e-5f);
}

// ---------------------------------------------------------------------------
// h = project(relu(BN(s1)))  NHWC bf16 (ch0 = time)
// ---------------------------------------------------------------------------
__global__ __launch_bounds__(256) void epi1(
    const unsigned short* __restrict__ s1, const float* __restrict__ murs,
    const float* __restrict__ g, const float* __restrict__ bt,
    unsigned short* __restrict__ h)
{
    int p = blockIdx.x * 256 + threadIdx.x;
    const unsigned short* sp = s1 + (size_t)p * 64;
    unsigned short ib[64], ob[64];
    #pragma unroll
    for (int k = 0; k < 8; ++k)
        *reinterpret_cast<short8*>(&ib[k * 8]) = *reinterpret_cast<const short8*>(sp + k * 8);
    float ssq = 0.f;
    #pragma unroll
    for (int c = 0; c < 63; ++c) {
        float v = b2f(ib[c]);
        v = g[c] * ((v - murs[c]) * murs[64 + c]) + bt[c];
        v = fmaxf(v, 0.f);
        ssq = fmaf(v, v, ssq);
        ob[c + 1] = f2b(v);
    }
    ob[0] = f2b(sqrtf(1.f + ssq));
    unsigned short* hp = h + (size_t)p * 64;
    #pragma unroll
    for (int k = 0; k < 8; ++k)
        *reinterpret_cast<short8*>(hp + k * 8) = *reinterpret_cast<short8*>(&ob[k * 8]);
}

// ---------------------------------------------------------------------------
// out = project(relu(BN(s2) + BN(sp)))  -> f32 NCHW (ch0 = time)
// ---------------------------------------------------------------------------
__global__ __launch_bounds__(256) void epi2(
    const unsigned short* __restrict__ s2, const unsigned short* __restrict__ spb,
    const float* __restrict__ murs2, const float* __restrict__ mursp,
    const float* __restrict__ g2, const float* __restrict__ bt2,
    const float* __restrict__ gp, const float* __restrict__ btp,
    float* __restrict__ out)
{
    int p = blockIdx.x * 256 + threadIdx.x;
    int b = p >> 14, rem = p & 16383;
    unsigned short i2[64], ip[64];
    #pragma unroll
    for (int k = 0; k < 8; ++k) {
        *reinterpret_cast<short8*>(&i2[k * 8]) =
            *reinterpret_cast<const short8*>(s2 + (size_t)p * 64 + k * 8);
        *reinterpret_cast<short8*>(&ip[k * 8]) =
            *reinterpret_cast<const short8*>(spb + (size_t)p * 64 + k * 8);
    }
    float* ob = out + (size_t)b * 64 * HW_ + rem;
    float ssq = 0.f;
    #pragma unroll
    for (int c = 0; c < 63; ++c) {
        float v2 = b2f(i2[c]);
        v2 = g2[c] * ((v2 - murs2[c]) * murs2[64 + c]) + bt2[c];
        float vp = b2f(ip[c]);
        vp = gp[c] * ((vp - mursp[c]) * mursp[64 + c]) + btp[c];
        float r = fmaxf(v2 + vp, 0.f);
        ssq = fmaf(r, r, ssq);
        ob[(size_t)(c + 1) * HW_] = r;
    }
    ob[0] = sqrtf(1.f + ssq);
}

// ---------------------------------------------------------------------------
extern "C" void kernel_launch(void* const* d_in, const int* in_sizes, int n_in,
                              void* d_out, int out_size, void* d_ws, size_t ws_size,
                              hipStream_t stream)
{
    (void)in_sizes; (void)n_in; (void)out_size; (void)ws_size;
    const float* x   = (const float*)d_in[0];
    const float* w1  = (const float*)d_in[1];
    const float* g1  = (const float*)d_in[3];
    const float* bt1 = (const float*)d_in[4];
    const float* w2  = (const float*)d_in[5];
    const float* g2  = (const float*)d_in[7];
    const float* bt2 = (const float*)d_in[8];
    const float* wp  = (const float*)d_in[9];
    const float* gp  = (const float*)d_in[11];
    const float* btp = (const float*)d_in[12];
    // biases b1/b2/bp are mathematically dead: BN immediately follows each conv.
    float* out = (float*)d_out;
    char* ws = (char*)d_ws;

    // ws layout (bytes)
    unsigned short* xc  = (unsigned short*)(ws);                 // 16,777,216 B
    unsigned short* s1  = (unsigned short*)(ws + 16777216);      // 33,554,432 B (reused as sp)
    unsigned short* h   = (unsigned short*)(ws + 50331648);      // 33,554,432 B
    unsigned short* s2  = (unsigned short*)(ws + 83886080);      // 33,554,432 B
    unsigned short* w1t = (unsigned short*)(ws + 117440512);     //     36,864 B
    unsigned short* w2t = (unsigned short*)(ws + 117477376);     //     73,728 B
    unsigned short* wpt = (unsigned short*)(ws + 117551104);     //      4,096 B
    float* sums = (float*)(ws + 117555200);                      //      1,536 B
    float* murs = (float*)(ws + 117556736);                      //      1,536 B

    hipMemsetAsync(sums, 0, 1536, stream);
    to_nhwc<<<1024, 256, 0, stream>>>(x, xc);
    prep_w<<<72, 256, 0, stream>>>(w1, w1t, 32, 3);
    prep_w<<<144, 256, 0, stream>>>(w2, w2t, 64, 3);
    prep_w<<<8, 256, 0, stream>>>(wp, wpt, 32, 1);

    conv_mfma<32, 3, 1><<<256, 512, 0, stream>>>(xc, w1t, s1, sums);
    finalize_stats<<<1, 64, 0, stream>>>(sums, murs);
    epi1<<<1024, 256, 0, stream>>>(s1, murs, g1, bt1, h);
    conv_mfma<64, 3, 1><<<256, 512, 0, stream>>>(h, w2t, s2, sums + 128);
    conv_mfma<32, 1, 0><<<256, 512, 0, stream>>>(xc, wpt, s1, sums + 256);  // sp reuses s1
    finalize_stats<<<2, 64, 0, stream>>>(sums + 128, murs + 128);
    epi2<<<1024, 256, 0, stream>>>(s2, s1, murs + 128, murs + 256,
                                   g2, bt2, gp, btp, out);
}